// Round 4
// baseline (145.896 us; speedup 1.0000x reference)
//
#include <hip/hip_runtime.h>
#include <cstdint>
#include <cstddef>

#define D 64

typedef float    f32x4 __attribute__((ext_vector_type(4)));
typedef short    s16x8 __attribute__((ext_vector_type(8)));
typedef uint32_t u32x4 __attribute__((ext_vector_type(4)));

// round-to-nearest-even fp32 -> bf16 (bits in low 16)
__device__ __forceinline__ uint32_t rne_bf16(float f) {
    uint32_t x = __float_as_uint(f);
    return (x + 0x7fffu + ((x >> 16) & 1u)) >> 16;
}
__device__ __forceinline__ float bf16lo(uint32_t u) { return __uint_as_float(u << 16); }
__device__ __forceinline__ float bf16hi(uint32_t u) { return __uint_as_float(u & 0xffff0000u); }

// Kernel 1: XWh[node] = bf16( X @ W )  via mfma_f32_16x16x32_bf16.
// Linearity: sum_j X[j] @ W == sum_j (X@W)[j] -- dense GEMM hoisted BEFORE
// the aggregation. Traffic identical to a pure cast kernel.
__global__ __launch_bounds__(256) void xw_gemm_kernel(
    const float* __restrict__ X, const float* __restrict__ W,
    uint32_t* __restrict__ XWh, int n_nodes)
{
    const int lane = threadIdx.x & 63;
    const int n = lane & 15;
    const int q = lane >> 4;

    // A-frag (W^T): A[m = c*16 + n][k = kb*32 + q*8 + j] = W[k*64 + c*16 + n]
    s16x8 Af[4][2];
#pragma unroll
    for (int c = 0; c < 4; ++c)
#pragma unroll
        for (int kb = 0; kb < 2; ++kb) {
            s16x8 af;
#pragma unroll
            for (int j = 0; j < 8; ++j) {
                const int k = kb * 32 + q * 8 + j;
                af[j] = (short)rne_bf16(W[k * D + c * 16 + n]);
            }
            Af[c][kb] = af;
        }

    const int n_tiles = (n_nodes + 15) / 16;
    const int gwave = (int)((blockIdx.x * blockDim.x + threadIdx.x) >> 6);
    const int nwaves = (int)((gridDim.x * blockDim.x) >> 6);

    for (int t = gwave; t < n_tiles; t += nwaves) {
        const int m0 = t * 16;
        int arow = m0 + n;
        if (arow >= n_nodes) arow = n_nodes - 1;  // clamp (tail tile)
        const float* xp = X + (size_t)arow * D;

        // B-frag: B[k = kb*32 + q*8 + j][n] = X[node n][k]
        s16x8 Bf[2];
#pragma unroll
        for (int kb = 0; kb < 2; ++kb) {
            const f32x4 x0 = __builtin_nontemporal_load((const f32x4*)(xp + kb * 32 + q * 8));
            const f32x4 x1 = __builtin_nontemporal_load((const f32x4*)(xp + kb * 32 + q * 8 + 4));
            s16x8 b;
            b[0] = (short)rne_bf16(x0.x); b[1] = (short)rne_bf16(x0.y);
            b[2] = (short)rne_bf16(x0.z); b[3] = (short)rne_bf16(x0.w);
            b[4] = (short)rne_bf16(x1.x); b[5] = (short)rne_bf16(x1.y);
            b[6] = (short)rne_bf16(x1.z); b[7] = (short)rne_bf16(x1.w);
            Bf[kb] = b;
        }

        const bool live = (m0 + n) < n_nodes;
#pragma unroll
        for (int c = 0; c < 4; ++c) {
            f32x4 z = {0.f, 0.f, 0.f, 0.f};
            z = __builtin_amdgcn_mfma_f32_16x16x32_bf16(Af[c][0], Bf[0], z, 0, 0, 0);
            z = __builtin_amdgcn_mfma_f32_16x16x32_bf16(Af[c][1], Bf[1], z, 0, 0, 0);
            if (live) {
                // lane holds features c*16 + q*4 + {0..3} of node m0+n
                uint2 o;
                o.x = rne_bf16(z[0]) | (rne_bf16(z[1]) << 16);
                o.y = rne_bf16(z[2]) | (rne_bf16(z[3]) << 16);
                *(uint2*)(XWh + (size_t)(m0 + n) * 32 + c * 8 + q * 2) = o;
            }
        }
    }
}

// Kernel 2: out[r] = fp32( sum_{e in row r} XWh[ci[e]] ), FOUR rows per wave.
//
// R3 post-mortem: 1 row/wave was bound by the per-row serial latency chain
// (rp -> ci -> gather -> reduce, ~6k cyc) x 100k short waves. Here one wave
// owns rows 4w..4w+3 and round-robins 8-edge chunks in three phases:
//   A: issue ci loads for all active rows (up to 4 in flight)
//   B: issue row gathers for all active rows (up to 4 in flight)
//   C: accumulate
// so one chain latency retires 4 rows' chunks. Scalar (wave-uniform) branches
// skip finished rows -- no wasted traffic; per-lane o<rem predication handles
// partial chunks via exec mask. rp is s_load'd via readfirstlane.
// o = lane>>3 (edge slot 0..7), p = lane&7 (feature octet, 16B per lane).
__global__ __launch_bounds__(256) void gather4_kernel(
    const uint32_t* __restrict__ XWh, const int* __restrict__ rp,
    const int* __restrict__ ci, float* __restrict__ out, int n_nodes)
{
    const int lane = threadIdx.x & 63;
    const int o = lane >> 3;
    const int p = lane & 7;
    const int gw = (int)((blockIdx.x * blockDim.x + threadIdx.x) >> 6);
    const int base = __builtin_amdgcn_readfirstlane(gw) * 4;
    if (base >= n_nodes) return;

    // rp[base .. base+4], clamped; uniform -> scalar loads
    int rpv[5];
#pragma unroll
    for (int k = 0; k < 5; ++k) {
        int r = base + k;
        if (r > n_nodes) r = n_nodes;
        rpv[k] = rp[r];
    }
    int e[4], e1[4];
#pragma unroll
    for (int r = 0; r < 4; ++r) {
        const bool ok = (base + r) < n_nodes;
        e[r]  = ok ? rpv[r]     : 0;
        e1[r] = ok ? rpv[r + 1] : 0;
    }

    float acc[4][8];
#pragma unroll
    for (int r = 0; r < 4; ++r)
#pragma unroll
        for (int j = 0; j < 8; ++j) acc[r][j] = 0.f;

    while (true) {
        bool any = false;
#pragma unroll
        for (int r = 0; r < 4; ++r) any = any | (e[r] < e1[r]);
        if (!any) break;

        // Phase A: index loads (predicated, up to 4 independent)
        int idx[4];
        bool v[4];
#pragma unroll
        for (int r = 0; r < 4; ++r) {
            v[r] = false;
            if (e[r] < e1[r]) {
                v[r] = o < (e1[r] - e[r]);
                if (v[r]) idx[r] = ci[e[r] + o];
            }
        }
        // Phase B: row gathers (predicated, up to 4 independent)
        u32x4 u[4];
#pragma unroll
        for (int r = 0; r < 4; ++r)
            if (v[r]) u[r] = *(const u32x4*)(XWh + (size_t)idx[r] * 32 + p * 4);
        // Phase C: accumulate + advance
#pragma unroll
        for (int r = 0; r < 4; ++r) {
            if (v[r]) {
#pragma unroll
                for (int k = 0; k < 4; ++k) {
                    acc[r][2 * k]     += bf16lo(u[r][k]);
                    acc[r][2 * k + 1] += bf16hi(u[r][k]);
                }
            }
            e[r] += 8;
        }
    }

    // Per-row reduce across the 8 edge slots (lane bits 3..5); lanes 0..7 hold
    // feature octet p. Four independent shfl chains -> good ILP.
#pragma unroll
    for (int r = 0; r < 4; ++r) {
#pragma unroll
        for (int j = 0; j < 8; ++j) {
            float vv = acc[r][j];
            vv += __shfl_xor(vv, 8, 64);
            vv += __shfl_xor(vv, 16, 64);
            vv += __shfl_xor(vv, 32, 64);
            acc[r][j] = vv;
        }
        const int row = base + r;
        if (lane < 8 && row < n_nodes) {
            f32x4 w0 = {acc[r][0], acc[r][1], acc[r][2], acc[r][3]};
            f32x4 w1 = {acc[r][4], acc[r][5], acc[r][6], acc[r][7]};
            *(f32x4*)(out + (size_t)row * D + p * 8)     = w0;
            *(f32x4*)(out + (size_t)row * D + p * 8 + 4) = w1;
        }
    }
}

// Fallback if ws can't hold XWh: fused per-row aggregate + shfl GEMM.
__global__ __launch_bounds__(256) void fused_kernel(
    const float* __restrict__ X, const float* __restrict__ W,
    const int* __restrict__ rp, const int* __restrict__ ci,
    float* __restrict__ out, int n_nodes)
{
    __shared__ float Wl[D * D];
    for (int i = threadIdx.x; i < D * D; i += 256) Wl[i] = W[i];
    __syncthreads();

    const int lane = threadIdx.x & 63;
    const int gwave = (int)((blockIdx.x * blockDim.x + threadIdx.x) >> 6);
    const int nwaves = (int)((gridDim.x * blockDim.x) >> 6);

    for (int row = gwave; row < n_nodes; row += nwaves) {
        int e0 = rp[row];
        int e1 = rp[row + 1];
        float acc = 0.f;
        for (int e = e0; e < e1; ++e) acc += X[ci[e] * D + lane];
        float sum = 0.f;
#pragma unroll
        for (int d = 0; d < D; ++d) {
            float a = __shfl(acc, d, 64);
            sum += a * Wl[d * D + lane];
        }
        out[row * D + lane] = sum;
    }
}

extern "C" void kernel_launch(void* const* d_in, const int* in_sizes, int n_in,
                              void* d_out, int out_size, void* d_ws, size_t ws_size,
                              hipStream_t stream)
{
    const float* X  = (const float*)d_in[0];   // [n, 64]
    const float* W  = (const float*)d_in[1];   // [64, 64]
    const int*   rp = (const int*)d_in[2];     // [n+1]
    const int*   ci = (const int*)d_in[3];     // [n_edges]
    float* out = (float*)d_out;

    const int n_nodes = in_sizes[2] - 1;
    const size_t row_bytes = 32 * sizeof(uint32_t);       // 128 B bf16 row
    const size_t need = (size_t)n_nodes * row_bytes;      // XWh only

    if (ws_size >= need) {
        uint32_t* XWh = (uint32_t*)d_ws;

        // K1: XWh = bf16(X @ W). ~1.5 tiles/wave; W-frag setup amortized.
        xw_gemm_kernel<<<1024, 256, 0, stream>>>(X, W, XWh, n_nodes);

        // K2: gather-aggregate rows of XWh -> fp32 out. 4 rows/wave.
        const int nwaves = (n_nodes + 3) / 4;             // 4 rows per wave
        const int gather_blocks = (nwaves + 3) / 4;       // 4 waves per block
        gather4_kernel<<<gather_blocks, 256, 0, stream>>>(XWh, rp, ci, out, n_nodes);
    } else {
        fused_kernel<<<2048, 256, 0, stream>>>(X, W, rp, ci, out, n_nodes);
    }
}

// Round 5
// 143.571 us; speedup vs baseline: 1.0162x; 1.0162x over previous
//
#include <hip/hip_runtime.h>
#include <cstdint>
#include <cstddef>

#define D 64

typedef float    f32x4 __attribute__((ext_vector_type(4)));
typedef short    s16x8 __attribute__((ext_vector_type(8)));
typedef uint32_t u32x4 __attribute__((ext_vector_type(4)));

// round-to-nearest-even fp32 -> bf16 (bits in low 16)
__device__ __forceinline__ uint32_t rne_bf16(float f) {
    uint32_t x = __float_as_uint(f);
    return (x + 0x7fffu + ((x >> 16) & 1u)) >> 16;
}
__device__ __forceinline__ float bf16lo(uint32_t u) { return __uint_as_float(u << 16); }
__device__ __forceinline__ float bf16hi(uint32_t u) { return __uint_as_float(u & 0xffff0000u); }

// Kernel 1: XWh[node] = bf16( X @ W )  via mfma_f32_16x16x32_bf16.
// Linearity: sum_j X[j] @ W == sum_j (X@W)[j] -- dense GEMM hoisted BEFORE
// the aggregation. Traffic identical to a pure cast kernel.
__global__ __launch_bounds__(256) void xw_gemm_kernel(
    const float* __restrict__ X, const float* __restrict__ W,
    uint32_t* __restrict__ XWh, int n_nodes)
{
    const int lane = threadIdx.x & 63;
    const int n = lane & 15;
    const int q = lane >> 4;

    // A-frag (W^T): A[m = c*16 + n][k = kb*32 + q*8 + j] = W[k*64 + c*16 + n]
    s16x8 Af[4][2];
#pragma unroll
    for (int c = 0; c < 4; ++c)
#pragma unroll
        for (int kb = 0; kb < 2; ++kb) {
            s16x8 af;
#pragma unroll
            for (int j = 0; j < 8; ++j) {
                const int k = kb * 32 + q * 8 + j;
                af[j] = (short)rne_bf16(W[k * D + c * 16 + n]);
            }
            Af[c][kb] = af;
        }

    const int n_tiles = (n_nodes + 15) / 16;
    const int gwave = (int)((blockIdx.x * blockDim.x + threadIdx.x) >> 6);
    const int nwaves = (int)((gridDim.x * blockDim.x) >> 6);

    for (int t = gwave; t < n_tiles; t += nwaves) {
        const int m0 = t * 16;
        int arow = m0 + n;
        if (arow >= n_nodes) arow = n_nodes - 1;  // clamp (tail tile)
        const float* xp = X + (size_t)arow * D;

        // B-frag: B[k = kb*32 + q*8 + j][n] = X[node n][k]
        s16x8 Bf[2];
#pragma unroll
        for (int kb = 0; kb < 2; ++kb) {
            const f32x4 x0 = __builtin_nontemporal_load((const f32x4*)(xp + kb * 32 + q * 8));
            const f32x4 x1 = __builtin_nontemporal_load((const f32x4*)(xp + kb * 32 + q * 8 + 4));
            s16x8 b;
            b[0] = (short)rne_bf16(x0.x); b[1] = (short)rne_bf16(x0.y);
            b[2] = (short)rne_bf16(x0.z); b[3] = (short)rne_bf16(x0.w);
            b[4] = (short)rne_bf16(x1.x); b[5] = (short)rne_bf16(x1.y);
            b[6] = (short)rne_bf16(x1.z); b[7] = (short)rne_bf16(x1.w);
            Bf[kb] = b;
        }

        const bool live = (m0 + n) < n_nodes;
#pragma unroll
        for (int c = 0; c < 4; ++c) {
            f32x4 z = {0.f, 0.f, 0.f, 0.f};
            z = __builtin_amdgcn_mfma_f32_16x16x32_bf16(Af[c][0], Bf[0], z, 0, 0, 0);
            z = __builtin_amdgcn_mfma_f32_16x16x32_bf16(Af[c][1], Bf[1], z, 0, 0, 0);
            if (live) {
                // lane holds features c*16 + q*4 + {0..3} of node m0+n
                uint2 o;
                o.x = rne_bf16(z[0]) | (rne_bf16(z[1]) << 16);
                o.y = rne_bf16(z[2]) | (rne_bf16(z[3]) << 16);
                *(uint2*)(XWh + (size_t)(m0 + n) * 32 + c * 8 + q * 2) = o;
            }
        }
    }
}

// Kernel 2: out[r] = fp32( sum_{e in row r} XWh[ci[e]] ), ONE row per wave,
// SINGLE-SHOT schedule.
//
// R4 post-mortem: the cost is the number of DEPENDENT memory hops per wave,
// and TLP (100k waves) is the concurrency engine -- not per-wave batching.
// Old chain: rp(vec load) -> [ci -> gather] per 16/8/tail step = 4-5 serial
// hops for an avg row. New chain: rp via s_load (row scalarized with
// readfirstlane) -> ALL chunk idx loads issued at once (<=8 in flight) ->
// ALL gathers issued at once (<=8 in flight) -> unpack. Deg <= 64 (98% of
// rows at deg~Exp(16)) = exactly 2 parallel vector-memory hops.
// o = lane>>3 (edge slot 0..7), p = lane&7 (feature octet, 16B per lane).
__global__ __launch_bounds__(256) void gather1shot_kernel(
    const uint32_t* __restrict__ XWh, const int* __restrict__ rp,
    const int* __restrict__ ci, float* __restrict__ out, int n_nodes)
{
    const int lane = threadIdx.x & 63;
    const int o = lane >> 3;
    const int p = lane & 7;
    const int gw = (int)((blockIdx.x * blockDim.x + threadIdx.x) >> 6);
    const int row = __builtin_amdgcn_readfirstlane(gw);  // wave-uniform -> SGPR
    if (row >= n_nodes) return;

    // row is scalar -> these compile to s_load (SMEM path, no VMEM hop)
    const int e0 = rp[row];
    const int e1 = rp[row + 1];

    float acc[8] = {0, 0, 0, 0, 0, 0, 0, 0};

    int e = e0;
    while (e < e1) {
        const int rem = e1 - e;  // scalar

        // Hop 1: ALL chunk index loads issued back-to-back (no dependencies)
        int idx[8];
        bool v[8];
#pragma unroll
        for (int t = 0; t < 8; ++t) {
            v[t] = (t * 8 + o) < rem;
            if (v[t]) idx[t] = ci[e + t * 8 + o];
        }
        // Hop 2: ALL row gathers issued back-to-back
        u32x4 u[8];
#pragma unroll
        for (int t = 0; t < 8; ++t)
            if (v[t]) u[t] = *(const u32x4*)(XWh + (size_t)idx[t] * 32 + p * 4);
        // Unpack + accumulate
#pragma unroll
        for (int t = 0; t < 8; ++t) {
            if (v[t]) {
#pragma unroll
                for (int k = 0; k < 4; ++k) {
                    acc[2 * k]     += bf16lo(u[t][k]);
                    acc[2 * k + 1] += bf16hi(u[t][k]);
                }
            }
        }
        e += 64;
    }

    // reduce across the 8 edge slots (lane bits 3..5); lanes 0..7 get sums
#pragma unroll
    for (int j = 0; j < 8; ++j) {
        float vv = acc[j];
        vv += __shfl_xor(vv, 8, 64);
        vv += __shfl_xor(vv, 16, 64);
        vv += __shfl_xor(vv, 32, 64);
        acc[j] = vv;
    }
    if (lane < 8) {
        // lane p holds features p*8 .. p*8+7 of this row, fp32
        f32x4 w0 = {acc[0], acc[1], acc[2], acc[3]};
        f32x4 w1 = {acc[4], acc[5], acc[6], acc[7]};
        *(f32x4*)(out + (size_t)row * D + p * 8)     = w0;
        *(f32x4*)(out + (size_t)row * D + p * 8 + 4) = w1;
    }
}

// Fallback if ws can't hold XWh: fused per-row aggregate + shfl GEMM.
__global__ __launch_bounds__(256) void fused_kernel(
    const float* __restrict__ X, const float* __restrict__ W,
    const int* __restrict__ rp, const int* __restrict__ ci,
    float* __restrict__ out, int n_nodes)
{
    __shared__ float Wl[D * D];
    for (int i = threadIdx.x; i < D * D; i += 256) Wl[i] = W[i];
    __syncthreads();

    const int lane = threadIdx.x & 63;
    const int gwave = (int)((blockIdx.x * blockDim.x + threadIdx.x) >> 6);
    const int nwaves = (int)((gridDim.x * blockDim.x) >> 6);

    for (int row = gwave; row < n_nodes; row += nwaves) {
        int e0 = rp[row];
        int e1 = rp[row + 1];
        float acc = 0.f;
        for (int e = e0; e < e1; ++e) acc += X[ci[e] * D + lane];
        float sum = 0.f;
#pragma unroll
        for (int d = 0; d < D; ++d) {
            float a = __shfl(acc, d, 64);
            sum += a * Wl[d * D + lane];
        }
        out[row * D + lane] = sum;
    }
}

extern "C" void kernel_launch(void* const* d_in, const int* in_sizes, int n_in,
                              void* d_out, int out_size, void* d_ws, size_t ws_size,
                              hipStream_t stream)
{
    const float* X  = (const float*)d_in[0];   // [n, 64]
    const float* W  = (const float*)d_in[1];   // [64, 64]
    const int*   rp = (const int*)d_in[2];     // [n+1]
    const int*   ci = (const int*)d_in[3];     // [n_edges]
    float* out = (float*)d_out;

    const int n_nodes = in_sizes[2] - 1;
    const size_t row_bytes = 32 * sizeof(uint32_t);       // 128 B bf16 row
    const size_t need = (size_t)n_nodes * row_bytes;      // XWh only

    if (ws_size >= need) {
        uint32_t* XWh = (uint32_t*)d_ws;

        // K1: XWh = bf16(X @ W). ~1.5 tiles/wave; W-frag setup amortized.
        xw_gemm_kernel<<<1024, 256, 0, stream>>>(X, W, XWh, n_nodes);

        // K2: gather-aggregate rows of XWh -> fp32 out. 1 row/wave, 1-shot.
        const int gather_blocks = (n_nodes + 3) / 4;  // 4 waves/block
        gather1shot_kernel<<<gather_blocks, 256, 0, stream>>>(XWh, rp, ci, out, n_nodes);
    } else {
        fused_kernel<<<2048, 256, 0, stream>>>(X, W, rp, ci, out, n_nodes);
    }
}